// Round 10
// baseline (140.883 us; speedup 1.0000x reference)
//
#include <hip/hip_runtime.h>

// B=8, N=1024, C=768, H=12, D=64.
// Pipeline: [convert x -> bf16] [transpose+convert Wqkv, Wproj -> Bt bf16]
//           [gemm_qkv R10: 128x128 BK=32 dbuf (32KB LDS -> 4 blocks/CU),
//            counted vmcnt(4), chunk-XOR swizzle]
//           [attn R6: exp-softmax, single-buffer K/Vt + reg-staged prefetch]
//           [gemm_proj R6: 64x128/4w -> f32 out + bias]
// R10: occupancy fix for qkv. R9 showed 64KB LDS -> 2 blocks/CU and 2.25
//      dispatch rounds (Occ 16%). BK=32 dbuf halves LDS -> 4 blocks/CU,
//      1.125 rounds; counted-vmcnt loop and swizzle retained.

typedef short  bf16x8_t __attribute__((ext_vector_type(8)));
typedef float  f32x4_t  __attribute__((ext_vector_type(4)));

static __device__ __forceinline__ unsigned short f2bf(float f) {
    union { float f; unsigned u; } v; v.f = f;
    unsigned r = v.u + 0x7fffu + ((v.u >> 16) & 1u);   // RNE
    return (unsigned short)(r >> 16);
}

typedef __attribute__((address_space(1))) const unsigned gas_u32;
typedef __attribute__((address_space(3))) unsigned las_u32;
static __device__ __forceinline__ void gload16(const void* g, void* l) {
    __builtin_amdgcn_global_load_lds((gas_u32*)g, (las_u32*)l, 16, 0, 0);
}

#define WAIT4 asm volatile("s_waitcnt vmcnt(4)" ::: "memory")
#define WAIT0 asm volatile("s_waitcnt vmcnt(0)" ::: "memory")
#define BAR   __builtin_amdgcn_s_barrier()

// ---- qkv BK=32 macros ------------------------------------------------------
// Stage one 128x32 bf16 tile (8KB): 2 gload_lds_dwordx4 per thread, linear
// LDS dest, chunk-XOR (4 chunks/row) applied on the GLOBAL source.
#define STAGE_Q(DST, SRC, K0)                                              \
    _Pragma("unroll")                                                      \
    for (int p_ = 0; p_ < 2; ++p_) {                                       \
        const int base_ = p_*256 + w64;                                    \
        const int i_ = base_ + lane;                                       \
        const int row_ = i_ >> 2;                                          \
        const int cb_ = ((i_ & 3) ^ (row_ & 3)) * 8;                       \
        gload16((SRC) + (size_t)row_*768 + (K0) + cb_, &(DST)[base_*8]);   \
    }

// One BK=32 K-tile: 8 ds_read_b128 + 16 MFMA per wave (read XOR undoes store).
#define COMPUTE_Q(AS, BS)                                                  \
    {                                                                      \
        bf16x8_t a_[4], b_[4];                                             \
        _Pragma("unroll")                                                  \
        for (int m_ = 0; m_ < 4; ++m_) {                                   \
            const int ra_ = wm*64 + m_*16 + l15;                           \
            a_[m_] = *(const bf16x8_t*)&(AS)[ra_*32 + (lhi ^ (ra_ & 3))*8];\
            const int rb_ = wn*64 + m_*16 + l15;                           \
            b_[m_] = *(const bf16x8_t*)&(BS)[rb_*32 + (lhi ^ (rb_ & 3))*8];\
        }                                                                  \
        _Pragma("unroll")                                                  \
        for (int m_ = 0; m_ < 4; ++m_)                                     \
            _Pragma("unroll")                                              \
            for (int n_ = 0; n_ < 4; ++n_)                                 \
                acc[m_][n_] = __builtin_amdgcn_mfma_f32_16x16x32_bf16(a_[m_], b_[n_], acc[m_][n_], 0, 0, 0); \
    }

// ---- proj staging/compute macros (R6, BK=64) -------------------------------
#define STAGE_TILE(DST, SRC, K0, NP, NT)                                   \
    _Pragma("unroll")                                                      \
    for (int p_ = 0; p_ < NP; ++p_) {                                      \
        const int base_ = p_*NT + wb;                                      \
        const int i_ = base_ + lane;                                       \
        const int row_ = i_ >> 3;                                          \
        const int cb_ = ((i_ & 7) ^ (row_ & 7)) * 8;                       \
        gload16((SRC) + (size_t)row_*768 + (K0) + cb_, &(DST)[base_*8]);   \
    }

#define COMPUTE_P(AS, BS)                                                  \
    {                                                                      \
        bf16x8_t a_[2][2], b_[2][4];                                       \
        _Pragma("unroll")                                                  \
        for (int ks_ = 0; ks_ < 2; ++ks_) {                                \
            _Pragma("unroll")                                              \
            for (int m_ = 0; m_ < 2; ++m_) {                               \
                const int ra_ = wm*32 + m_*16 + l15;                       \
                a_[ks_][m_] = *(const bf16x8_t*)&(AS)[ra_*64 + ((ks_*4 + lhi) ^ (ra_ & 7))*8]; \
            }                                                              \
            _Pragma("unroll")                                              \
            for (int n_ = 0; n_ < 4; ++n_) {                               \
                const int rb_ = wn*64 + n_*16 + l15;                       \
                b_[ks_][n_] = *(const bf16x8_t*)&(BS)[rb_*64 + ((ks_*4 + lhi) ^ (rb_ & 7))*8]; \
            }                                                              \
        }                                                                  \
        _Pragma("unroll")                                                  \
        for (int m_ = 0; m_ < 2; ++m_)                                     \
            _Pragma("unroll")                                              \
            for (int n_ = 0; n_ < 4; ++n_) {                               \
                acc[m_][n_] = __builtin_amdgcn_mfma_f32_16x16x32_bf16(a_[0][m_], b_[0][n_], acc[m_][n_], 0, 0, 0); \
                acc[m_][n_] = __builtin_amdgcn_mfma_f32_16x16x32_bf16(a_[1][m_], b_[1][n_], acc[m_][n_], 0, 0, 0); \
            }                                                              \
    }

// ---------------- pre-pass: x f32 -> bf16 (same layout)
__global__ __launch_bounds__(256) void convert_x(
    const float* __restrict__ src, unsigned short* __restrict__ dst)
{
    const int i = blockIdx.x * 256 + threadIdx.x;
    const float4 v = ((const float4*)src)[i];
    ushort4 o; o.x = f2bf(v.x); o.y = f2bf(v.y); o.z = f2bf(v.z); o.w = f2bf(v.w);
    ((ushort4*)dst)[i] = o;
}

// ---------------- pre-pass: W [R][C] f32 -> Wt [C][R] bf16
__global__ __launch_bounds__(256) void transpose_cvt(
    const float* __restrict__ src, unsigned short* __restrict__ dst, int R, int C)
{
    __shared__ unsigned short tile[32][33];
    const int tx = threadIdx.x & 31, ty = threadIdx.x >> 5;
    const int bx = blockIdx.x, by = blockIdx.y;
    #pragma unroll
    for (int j = 0; j < 32; j += 8)
        tile[ty + j][tx] = f2bf(src[(size_t)(by*32 + ty + j) * C + bx*32 + tx]);
    __syncthreads();
    #pragma unroll
    for (int j = 0; j < 32; j += 8)
        dst[(size_t)(bx*32 + ty + j) * R + by*32 + tx] = tile[tx][ty + j];
}

// ---------------- GEMM1 (R10): 128x128, BK=32 dbuf, counted vmcnt(4)
__global__ __launch_bounds__(256, 4) void gemm_qkv_bf16(
    const unsigned short* __restrict__ A, const unsigned short* __restrict__ Bt,
    const float* __restrict__ bias,
    unsigned short* __restrict__ q, unsigned short* __restrict__ kO,
    unsigned short* __restrict__ vT)
{
    __shared__ unsigned short As0[128*32], As1[128*32];   // 8KB each
    __shared__ unsigned short Bs0[128*32], Bs1[128*32];   // total 32KB
    const int tid = threadIdx.x;
    const int id = blockIdx.x;                 // 1152 blocks, 1152%8==0
    const int swz = (id & 7) * 144 + (id >> 3);
    const int n0 = (swz % 18) * 128, m0 = (swz / 18) * 128;

    const int lane = tid & 63, w = tid >> 6;
    const int l15 = lane & 15, lhi = lane >> 4;
    const int wm = w >> 1, wn = w & 1;
    const int w64 = tid & 192;

    const unsigned short* Ab = A  + (size_t)m0 * 768;
    const unsigned short* Bb = Bt + (size_t)n0 * 768;

    f32x4_t acc[4][4] = {};

    // prologue: tiles 0,1 in flight
    STAGE_Q(As0, Ab, 0)
    STAGE_Q(Bs0, Bb, 0)
    STAGE_Q(As1, Ab, 32)
    STAGE_Q(Bs1, Bb, 32)

    #pragma unroll 1
    for (int t = 0; t < 12; ++t) {
        WAIT4; BAR;                            // tile 2t landed; 2t+1 flying
        COMPUTE_Q(As0, Bs0)
        BAR;
        if (t < 11) {
            STAGE_Q(As0, Ab, t*64 + 64)        // tile 2t+2
            STAGE_Q(Bs0, Bb, t*64 + 64)
            WAIT4;                             // tile 2t+1 landed
        } else {
            WAIT0;
        }
        BAR;
        COMPUTE_Q(As1, Bs1)
        BAR;
        if (t < 11) {
            STAGE_Q(As1, Ab, t*64 + 96)        // tile 2t+3
            STAGE_Q(Bs1, Bb, t*64 + 96)
        }
    }

    #pragma unroll
    for (int n = 0; n < 4; ++n) {
        const int gcol = n0 + wn*64 + n*16 + l15;         // 0..2303
        const int kk = gcol / 768;                        // 0=q,1=k,2=v
        const int r  = gcol - kk*768;
        const int h  = r >> 6, d = r & 63;
        const float bv = bias[gcol];
        const float sc = (kk == 0) ? 0.125f : 1.0f;
        #pragma unroll
        for (int m = 0; m < 4; ++m) {
            const int grow_base = m0 + wm*64 + m*16 + lhi*4;
            #pragma unroll
            for (int reg = 0; reg < 4; ++reg) {
                const int grow = grow_base + reg;         // b*1024+seq
                const int bb = grow >> 10, seq = grow & 1023;
                const unsigned short ov = f2bf((acc[m][n][reg] + bv) * sc);
                const size_t bh = (size_t)bb*12 + h;
                if (kk == 0)      q [ (bh*1024 + seq)*64 + d ] = ov;
                else if (kk == 1) kO[ (bh*1024 + seq)*64 + d ] = ov;
                else              vT[ (bh*64 + d)*1024 + seq ] = ov;
            }
        }
    }
}

// ---------------- Attention (R6): single-buffer K/Vt + reg-staged prefetch
__global__ __launch_bounds__(256, 5) void attn2(
    const unsigned short* __restrict__ q, const unsigned short* __restrict__ k,
    const unsigned short* __restrict__ vT, unsigned short* __restrict__ obuf)
{
    __shared__ unsigned short Ks[64 * 72];
    __shared__ unsigned short Vs[64 * 72];
    __shared__ unsigned short P[4][16 * 72];
    const int tid = threadIdx.x;
    const int id = blockIdx.x;                 // 1536 blocks
    const int swz = (id & 7) * 192 + (id >> 3);
    const int qt = swz & 15, bh = swz >> 4;

    const int lane = tid & 63, w = tid >> 6;
    const int l15 = lane & 15, lhi = lane >> 4;
    const unsigned short* qp = q  + (size_t)bh * 65536;
    const unsigned short* kp = k  + (size_t)bh * 65536;
    const unsigned short* vp = vT + (size_t)bh * 65536;  // [64 d][1024 n]

    bf16x8_t qf[2];
    const int qrow = qt*64 + w*16 + l15;
    #pragma unroll
    for (int ks = 0; ks < 2; ++ks)
        qf[ks] = *(const bf16x8_t*)(qp + (size_t)qrow*64 + ks*32 + lhi*8);

    f32x4_t acco[4] = {};
    float lsum[4] = {0.f, 0.f, 0.f, 0.f};
    unsigned short* Pw = P[w];

    bf16x8_t kr[2], vr[2];
    #pragma unroll
    for (int p = 0; p < 2; ++p) {
        const int idx = p*256 + tid;
        const int r8 = idx >> 3, cb = (idx & 7) * 8;
        kr[p] = *(const bf16x8_t*)(kp + (size_t)r8*64 + cb);
        vr[p] = *(const bf16x8_t*)(vp + (size_t)r8*1024 + cb);
    }
    #pragma unroll
    for (int p = 0; p < 2; ++p) {
        const int idx = p*256 + tid;
        const int r8 = idx >> 3, cb = (idx & 7) * 8;
        *(bf16x8_t*)&Ks[r8*72 + cb] = kr[p];
        *(bf16x8_t*)&Vs[r8*72 + cb] = vr[p];
    }

    for (int kt = 0; kt < 16; ++kt) {
        __syncthreads();
        if (kt < 15) {
            #pragma unroll
            for (int p = 0; p < 2; ++p) {
                const int idx = p*256 + tid;
                const int r8 = idx >> 3, cb = (idx & 7) * 8;
                kr[p] = *(const bf16x8_t*)(kp + (size_t)((kt+1)*64 + r8)*64 + cb);
                vr[p] = *(const bf16x8_t*)(vp + (size_t)r8*1024 + (kt+1)*64 + cb);
            }
        }

        f32x4_t accs[4] = {};
        __builtin_amdgcn_s_setprio(1);
        #pragma unroll
        for (int c = 0; c < 4; ++c)
            #pragma unroll
            for (int ks = 0; ks < 2; ++ks) {
                bf16x8_t kf = *(const bf16x8_t*)&Ks[(c*16 + l15)*72 + ks*32 + lhi*8];
                accs[c] = __builtin_amdgcn_mfma_f32_16x16x32_bf16(qf[ks], kf, accs[c], 0, 0, 0);
            }
        __builtin_amdgcn_s_setprio(0);

        #pragma unroll
        for (int c = 0; c < 4; ++c)
            #pragma unroll
            for (int r = 0; r < 4; ++r) {
                const float pv = __expf(accs[c][r]);
                lsum[r] += pv;
                Pw[(lhi*4 + r)*72 + c*16 + l15] = f2bf(pv);
            }

        bf16x8_t pf[2];
        #pragma unroll
        for (int ks = 0; ks < 2; ++ks)
            pf[ks] = *(const bf16x8_t*)&Pw[l15*72 + ks*32 + lhi*8];
        __builtin_amdgcn_s_setprio(1);
        #pragma unroll
        for (int n = 0; n < 4; ++n)
            #pragma unroll
            for (int ks = 0; ks < 2; ++ks) {
                bf16x8_t vf = *(const bf16x8_t*)&Vs[(n*16 + l15)*72 + ks*32 + lhi*8];
                acco[n] = __builtin_amdgcn_mfma_f32_16x16x32_bf16(pf[ks], vf, acco[n], 0, 0, 0);
            }
        __builtin_amdgcn_s_setprio(0);

        __syncthreads();
        if (kt < 15) {
            #pragma unroll
            for (int p = 0; p < 2; ++p) {
                const int idx = p*256 + tid;
                const int r8 = idx >> 3, cb = (idx & 7) * 8;
                *(bf16x8_t*)&Ks[r8*72 + cb] = kr[p];
                *(bf16x8_t*)&Vs[r8*72 + cb] = vr[p];
            }
        }
    }

    #pragma unroll
    for (int r = 0; r < 4; ++r)
        #pragma unroll
        for (int off = 1; off <= 8; off <<= 1)
            lsum[r] += __shfl_xor(lsum[r], off, 64);

    const int b = bh / 12, h = bh % 12;
    #pragma unroll
    for (int n = 0; n < 4; ++n)
        #pragma unroll
        for (int r = 0; r < 4; ++r) {
            const int seq = qt*64 + w*16 + lhi*4 + r;
            obuf[((size_t)(b*1024 + seq))*768 + h*64 + n*16 + l15] = f2bf(acco[n][r] / lsum[r]);
        }
}

// ---------------- GEMM2 (R6): 64x128 tile, 4 waves, 24KB buffer
__global__ __launch_bounds__(256, 4) void gemm_proj_bf16(
    const unsigned short* __restrict__ A, const unsigned short* __restrict__ Bt,
    const float* __restrict__ bias, float* __restrict__ out)
{
    __shared__ unsigned short As[64*64];
    __shared__ unsigned short Bs[128*64];
    const int tid = threadIdx.x;
    const int id = blockIdx.x;              // 768 blocks = 3/CU exact
    const int swz = (id & 7) * 96 + (id >> 3);
    const int n0 = (swz % 6) * 128, m0 = (swz / 6) * 64;

    const int lane = tid & 63, w = tid >> 6;
    const int l15 = lane & 15, lhi = lane >> 4;
    const int wm = w >> 1, wn = w & 1;
    const int wb = tid & 192;

    const unsigned short* Ab = A  + (size_t)m0 * 768;
    const unsigned short* Bb = Bt + (size_t)n0 * 768;

    f32x4_t acc[2][4] = {};

    #pragma unroll 1
    for (int t = 0; t < 12; ++t) {
        STAGE_TILE(As, Ab, t*64, 2, 256)
        STAGE_TILE(Bs, Bb, t*64, 4, 256)
        WAIT0; BAR;
        COMPUTE_P(As, Bs)
        BAR;
    }

    #pragma unroll
    for (int n = 0; n < 4; ++n) {
        const int gcol = n0 + wn*64 + n*16 + l15;
        const float bv = bias[gcol];
        #pragma unroll
        for (int m = 0; m < 2; ++m) {
            const int grow_base = m0 + wm*32 + m*16 + lhi*4;
            #pragma unroll
            for (int reg = 0; reg < 4; ++reg)
                out[(size_t)(grow_base + reg)*768 + gcol] = acc[m][n][reg] + bv;
        }
    }
}

extern "C" void kernel_launch(void* const* d_in, const int* in_sizes, int n_in,
                              void* d_out, int out_size, void* d_ws, size_t ws_size,
                              hipStream_t stream) {
    const float* x     = (const float*)d_in[0];
    const float* Wqkv  = (const float*)d_in[1];
    const float* bqkv  = (const float*)d_in[2];
    const float* Wproj = (const float*)d_in[3];
    const float* bproj = (const float*)d_in[4];
    float* out = (float*)d_out;
    unsigned short* ws = (unsigned short*)d_ws;

    unsigned short* xb    = ws;                       // 6291456
    unsigned short* obuf  = ws;                       // alias (xb dead after gemm_qkv)
    unsigned short* wqt   = ws + 6291456u;            // 1769472
    unsigned short* wpt   = ws + 8060928u;            // 589824
    unsigned short* qb    = ws + 8650752u;            // 6291456
    unsigned short* kb    = ws + 14942208u;           // 6291456
    unsigned short* vTb   = ws + 21233664u;           // 6291456

    convert_x     <<<6144, 256, 0, stream>>>(x, xb);
    transpose_cvt <<<dim3(72, 24), 256, 0, stream>>>(Wqkv, wqt, 768, 2304);
    transpose_cvt <<<dim3(24, 24), 256, 0, stream>>>(Wproj, wpt, 768, 768);
    gemm_qkv_bf16 <<<1152, 256, 0, stream>>>(xb, wqt, bqkv, qb, kb, vTb);
    attn2         <<<1536, 256, 0, stream>>>(qb, kb, vTb, obuf);
    gemm_proj_bf16<<<768, 256, 0, stream>>>(obuf, wpt, bproj, out);
}

// Round 11
// 140.542 us; speedup vs baseline: 1.0024x; 1.0024x over previous
//
#include <hip/hip_runtime.h>

// B=8, N=1024, C=768, H=12, D=64.
// Pipeline: [convert x -> bf16 FRAGMENT layout xf]
//           [frag Wqkv -> bf16 FRAGMENT layout wf] [transpose Wproj -> Wpt]
//           [gemm_qkv R11: NO LDS, NO barriers — frags coalesced from global]
//           [attn R6: exp-softmax, single-buffer K/Vt + reg-staged prefetch]
//           [gemm_proj R6: 64x128/4w -> f32 out + bias]
// R11: fix R8's failure (strided frag loads, ~25 transactions/instr) by
//      pre-permuting operands into MFMA-fragment order in the prepasses:
//      frag(mi,ki) = 1KB contiguous, wave reads it as lane*16B -> 1 transaction.
//      Fragment layouts: xf[mi 0..511][ki 0..23][lane][8]  (elem (l,j) =
//      x[mi*16+(l&15)][ki*32+(l>>4)*8+j]);  wf[ni 0..143][ki][lane][8]
//      (elem (l,j) = Wqkv[ki*32+(l>>4)*8+j][ni*16+(l&15)]).

typedef short  bf16x8_t __attribute__((ext_vector_type(8)));
typedef float  f32x4_t  __attribute__((ext_vector_type(4)));

static __device__ __forceinline__ unsigned short f2bf(float f) {
    union { float f; unsigned u; } v; v.f = f;
    unsigned r = v.u + 0x7fffu + ((v.u >> 16) & 1u);   // RNE
    return (unsigned short)(r >> 16);
}

typedef __attribute__((address_space(1))) const unsigned gas_u32;
typedef __attribute__((address_space(3))) unsigned las_u32;
static __device__ __forceinline__ void gload16(const void* g, void* l) {
    __builtin_amdgcn_global_load_lds((gas_u32*)g, (las_u32*)l, 16, 0, 0);
}

#define WAIT0 asm volatile("s_waitcnt vmcnt(0)" ::: "memory")
#define BAR   __builtin_amdgcn_s_barrier()

// ---- proj staging/compute macros (R6, BK=64) -------------------------------
#define STAGE_TILE(DST, SRC, K0, NP, NT)                                   \
    _Pragma("unroll")                                                      \
    for (int p_ = 0; p_ < NP; ++p_) {                                      \
        const int base_ = p_*NT + wb;                                      \
        const int i_ = base_ + lane;                                       \
        const int row_ = i_ >> 3;                                          \
        const int cb_ = ((i_ & 7) ^ (row_ & 7)) * 8;                       \
        gload16((SRC) + (size_t)row_*768 + (K0) + cb_, &(DST)[base_*8]);   \
    }

#define COMPUTE_P(AS, BS)                                                  \
    {                                                                      \
        bf16x8_t a_[2][2], b_[2][4];                                       \
        _Pragma("unroll")                                                  \
        for (int ks_ = 0; ks_ < 2; ++ks_) {                                \
            _Pragma("unroll")                                              \
            for (int m_ = 0; m_ < 2; ++m_) {                               \
                const int ra_ = wm*32 + m_*16 + l15;                       \
                a_[ks_][m_] = *(const bf16x8_t*)&(AS)[ra_*64 + ((ks_*4 + lhi) ^ (ra_ & 7))*8]; \
            }                                                              \
            _Pragma("unroll")                                              \
            for (int n_ = 0; n_ < 4; ++n_) {                               \
                const int rb_ = wn*64 + n_*16 + l15;                       \
                b_[ks_][n_] = *(const bf16x8_t*)&(BS)[rb_*64 + ((ks_*4 + lhi) ^ (rb_ & 7))*8]; \
            }                                                              \
        }                                                                  \
        _Pragma("unroll")                                                  \
        for (int m_ = 0; m_ < 2; ++m_)                                     \
            _Pragma("unroll")                                              \
            for (int n_ = 0; n_ < 4; ++n_) {                               \
                acc[m_][n_] = __builtin_amdgcn_mfma_f32_16x16x32_bf16(a_[0][m_], b_[0][n_], acc[m_][n_], 0, 0, 0); \
                acc[m_][n_] = __builtin_amdgcn_mfma_f32_16x16x32_bf16(a_[1][m_], b_[1][n_], acc[m_][n_], 0, 0, 0); \
            }                                                              \
    }

// ---------------- pre-pass: x f32 -> xf (A-fragment layout, bf16)
__global__ __launch_bounds__(256) void convert_x_frag(
    const float* __restrict__ src, unsigned short* __restrict__ dst)
{
    const int t = blockIdx.x * 256 + threadIdx.x;     // 786432 threads
    const int l = t & 63, fi = t >> 6;
    const int ki = fi % 24, mi = fi / 24;             // mi 0..511
    const int row = mi*16 + (l & 15), col = ki*32 + (l >> 4)*8;
    const float4 v0 = *(const float4*)(src + (size_t)row*768 + col);
    const float4 v1 = *(const float4*)(src + (size_t)row*768 + col + 4);
    ushort4 o0, o1;
    o0.x = f2bf(v0.x); o0.y = f2bf(v0.y); o0.z = f2bf(v0.z); o0.w = f2bf(v0.w);
    o1.x = f2bf(v1.x); o1.y = f2bf(v1.y); o1.z = f2bf(v1.z); o1.w = f2bf(v1.w);
    *(ushort4*)(dst + (size_t)t*8)     = o0;          // coalesced 16B/lane
    *(ushort4*)(dst + (size_t)t*8 + 4) = o1;
}

// ---------------- pre-pass: Wqkv [768][2304] f32 -> wf (B-fragment layout)
__global__ __launch_bounds__(256) void frag_wq(
    const float* __restrict__ W, unsigned short* __restrict__ dst)
{
    const int t = blockIdx.x * 256 + threadIdx.x;     // 221184 threads
    const int l = t & 63, fi = t >> 6;
    const int ki = fi % 24, ni = fi / 24;             // ni 0..143
    const int row0 = ki*32 + (l >> 4)*8;              // k index base
    const int col  = ni*16 + (l & 15);                // output col (0..2303)
    ushort4 o0, o1;
    o0.x = f2bf(W[(size_t)(row0+0)*2304 + col]);
    o0.y = f2bf(W[(size_t)(row0+1)*2304 + col]);
    o0.z = f2bf(W[(size_t)(row0+2)*2304 + col]);
    o0.w = f2bf(W[(size_t)(row0+3)*2304 + col]);
    o1.x = f2bf(W[(size_t)(row0+4)*2304 + col]);
    o1.y = f2bf(W[(size_t)(row0+5)*2304 + col]);
    o1.z = f2bf(W[(size_t)(row0+6)*2304 + col]);
    o1.w = f2bf(W[(size_t)(row0+7)*2304 + col]);
    *(ushort4*)(dst + (size_t)t*8)     = o0;
    *(ushort4*)(dst + (size_t)t*8 + 4) = o1;
}

// ---------------- pre-pass: W [R][C] f32 -> Wt [C][R] bf16 (for proj)
__global__ __launch_bounds__(256) void transpose_cvt(
    const float* __restrict__ src, unsigned short* __restrict__ dst, int R, int C)
{
    __shared__ unsigned short tile[32][33];
    const int tx = threadIdx.x & 31, ty = threadIdx.x >> 5;
    const int bx = blockIdx.x, by = blockIdx.y;
    #pragma unroll
    for (int j = 0; j < 32; j += 8)
        tile[ty + j][tx] = f2bf(src[(size_t)(by*32 + ty + j) * C + bx*32 + tx]);
    __syncthreads();
    #pragma unroll
    for (int j = 0; j < 32; j += 8)
        dst[(size_t)(bx*32 + ty + j) * R + by*32 + tx] = tile[tx][ty + j];
}

// ---------------- GEMM1 (R11): no-LDS fragment GEMM, 128x128, 4 waves
#define LOADF(AA, BB, KI)                                                  \
    _Pragma("unroll")                                                      \
    for (int m_ = 0; m_ < 4; ++m_) {                                       \
        AA[m_] = *(const bf16x8_t*)(Af + ((size_t)(m_*24 + (KI)))*512 + lane*8); \
        BB[m_] = *(const bf16x8_t*)(Bf + ((size_t)(m_*24 + (KI)))*512 + lane*8); \
    }

#define MFMA_STEP(AA, BB)                                                  \
    _Pragma("unroll")                                                      \
    for (int m_ = 0; m_ < 4; ++m_)                                         \
        _Pragma("unroll")                                                  \
        for (int n_ = 0; n_ < 4; ++n_)                                     \
            acc[m_][n_] = __builtin_amdgcn_mfma_f32_16x16x32_bf16(AA[m_], BB[n_], acc[m_][n_], 0, 0, 0);

__global__ __launch_bounds__(256, 3) void gemm_qkv_bf16(
    const unsigned short* __restrict__ xf, const unsigned short* __restrict__ wf,
    const float* __restrict__ bias,
    unsigned short* __restrict__ q, unsigned short* __restrict__ kO,
    unsigned short* __restrict__ vT)
{
    const int tid = threadIdx.x;
    const int id = blockIdx.x;                 // 1152 blocks, 1152%8==0
    const int swz = (id & 7) * 144 + (id >> 3);
    const int nb = swz % 18, mb = swz / 18;
    const int n0 = nb * 128, m0 = mb * 128;

    const int lane = tid & 63, w = tid >> 6;
    const int l15 = lane & 15, lhi = lane >> 4;
    const int wm = w >> 1, wn = w & 1;         // 2x2 wave grid

    // wave's fragment panels: 4 mi-tiles (wm) x 24 ki, 4 ni-tiles (wn) x 24 ki
    const unsigned short* Af = xf + (size_t)(mb*8 + wm*4) * 24 * 512;
    const unsigned short* Bf = wf + (size_t)(nb*8 + wn*4) * 24 * 512;

    f32x4_t acc[4][4] = {};
    bf16x8_t a0[4], b0[4], a1[4], b1[4];

    LOADF(a0, b0, 0)
    #pragma unroll 1
    for (int t = 0; t < 12; ++t) {
        LOADF(a1, b1, 2*t + 1)
        MFMA_STEP(a0, b0)
        if (t < 11) { LOADF(a0, b0, 2*t + 2) }
        MFMA_STEP(a1, b1)
    }

    // epilogue: qkv scatter (unchanged)
    #pragma unroll
    for (int n = 0; n < 4; ++n) {
        const int gcol = n0 + wn*64 + n*16 + l15;         // 0..2303
        const int kk = gcol / 768;                        // 0=q,1=k,2=v
        const int r  = gcol - kk*768;
        const int h  = r >> 6, d = r & 63;
        const float bv = bias[gcol];
        const float sc = (kk == 0) ? 0.125f : 1.0f;
        #pragma unroll
        for (int m = 0; m < 4; ++m) {
            const int grow_base = m0 + wm*64 + m*16 + lhi*4;
            #pragma unroll
            for (int reg = 0; reg < 4; ++reg) {
                const int grow = grow_base + reg;         // b*1024+seq
                const int bb = grow >> 10, seq = grow & 1023;
                const unsigned short ov = f2bf((acc[m][n][reg] + bv) * sc);
                const size_t bh = (size_t)bb*12 + h;
                if (kk == 0)      q [ (bh*1024 + seq)*64 + d ] = ov;
                else if (kk == 1) kO[ (bh*1024 + seq)*64 + d ] = ov;
                else              vT[ (bh*64 + d)*1024 + seq ] = ov;
            }
        }
    }
}

// ---------------- Attention (R6): single-buffer K/Vt + reg-staged prefetch
__global__ __launch_bounds__(256, 5) void attn2(
    const unsigned short* __restrict__ q, const unsigned short* __restrict__ k,
    const unsigned short* __restrict__ vT, unsigned short* __restrict__ obuf)
{
    __shared__ unsigned short Ks[64 * 72];
    __shared__ unsigned short Vs[64 * 72];
    __shared__ unsigned short P[4][16 * 72];
    const int tid = threadIdx.x;
    const int id = blockIdx.x;                 // 1536 blocks
    const int swz = (id & 7) * 192 + (id >> 3);
    const int qt = swz & 15, bh = swz >> 4;

    const int lane = tid & 63, w = tid >> 6;
    const int l15 = lane & 15, lhi = lane >> 4;
    const unsigned short* qp = q  + (size_t)bh * 65536;
    const unsigned short* kp = k  + (size_t)bh * 65536;
    const unsigned short* vp = vT + (size_t)bh * 65536;  // [64 d][1024 n]

    bf16x8_t qf[2];
    const int qrow = qt*64 + w*16 + l15;
    #pragma unroll
    for (int ks = 0; ks < 2; ++ks)
        qf[ks] = *(const bf16x8_t*)(qp + (size_t)qrow*64 + ks*32 + lhi*8);

    f32x4_t acco[4] = {};
    float lsum[4] = {0.f, 0.f, 0.f, 0.f};
    unsigned short* Pw = P[w];

    bf16x8_t kr[2], vr[2];
    #pragma unroll
    for (int p = 0; p < 2; ++p) {
        const int idx = p*256 + tid;
        const int r8 = idx >> 3, cb = (idx & 7) * 8;
        kr[p] = *(const bf16x8_t*)(kp + (size_t)r8*64 + cb);
        vr[p] = *(const bf16x8_t*)(vp + (size_t)r8*1024 + cb);
    }
    #pragma unroll
    for (int p = 0; p < 2; ++p) {
        const int idx = p*256 + tid;
        const int r8 = idx >> 3, cb = (idx & 7) * 8;
        *(bf16x8_t*)&Ks[r8*72 + cb] = kr[p];
        *(bf16x8_t*)&Vs[r8*72 + cb] = vr[p];
    }

    for (int kt = 0; kt < 16; ++kt) {
        __syncthreads();
        if (kt < 15) {
            #pragma unroll
            for (int p = 0; p < 2; ++p) {
                const int idx = p*256 + tid;
                const int r8 = idx >> 3, cb = (idx & 7) * 8;
                kr[p] = *(const bf16x8_t*)(kp + (size_t)((kt+1)*64 + r8)*64 + cb);
                vr[p] = *(const bf16x8_t*)(vp + (size_t)r8*1024 + (kt+1)*64 + cb);
            }
        }

        f32x4_t accs[4] = {};
        __builtin_amdgcn_s_setprio(1);
        #pragma unroll
        for (int c = 0; c < 4; ++c)
            #pragma unroll
            for (int ks = 0; ks < 2; ++ks) {
                bf16x8_t kf = *(const bf16x8_t*)&Ks[(c*16 + l15)*72 + ks*32 + lhi*8];
                accs[c] = __builtin_amdgcn_mfma_f32_16x16x32_bf16(qf[ks], kf, accs[c], 0, 0, 0);
            }
        __builtin_amdgcn_s_setprio(0);

        #pragma unroll
        for (int c = 0; c < 4; ++c)
            #pragma unroll
            for (int r = 0; r < 4; ++r) {
                const float pv = __expf(accs[c][r]);
                lsum[r] += pv;
                Pw[(lhi*4 + r)*72 + c*16 + l15] = f2bf(pv);
            }

        bf16x8_t pf[2];
        #pragma unroll
        for (int ks = 0; ks < 2; ++ks)
            pf[ks] = *(const bf16x8_t*)&Pw[l15*72 + ks*32 + lhi*8];
        __builtin_amdgcn_s_setprio(1);
        #pragma unroll
        for (int n = 0; n < 4; ++n)
            #pragma unroll
            for (int ks = 0; ks < 2; ++ks) {
                bf16x8_t vf = *(const bf16x8_t*)&Vs[(n*16 + l15)*72 + ks*32 + lhi*8];
                acco[n] = __builtin_amdgcn_mfma_f32_16x16x32_bf16(pf[ks], vf, acco[n], 0, 0, 0);
            }
        __builtin_amdgcn_s_setprio(0);

        __syncthreads();
        if (kt < 15) {
            #pragma unroll
            for (int p = 0; p < 2; ++p) {
                const int idx = p*256 + tid;
                const int r8 = idx >> 3, cb = (idx & 7) * 8;
                *(bf16x8_t*)&Ks[r8*72 + cb] = kr[p];
                *(bf16x8_t*)&Vs[r8*72 + cb] = vr[p];
            }
        }
    }

    #pragma unroll
    for (int r = 0; r < 4; ++r)
        #pragma unroll
        for (int off = 1; off <= 8; off <<= 1)
            lsum[r] += __shfl_xor(lsum[r], off, 64);

    const int b = bh / 12, h = bh % 12;
    #pragma unroll
    for (int n = 0; n < 4; ++n)
        #pragma unroll
        for (int r = 0; r < 4; ++r) {
            const int seq = qt*64 + w*16 + lhi*4 + r;
            obuf[((size_t)(b*1024 + seq))*768 + h*64 + n*16 + l15] = f2bf(acco[n][r] / lsum[r]);
        }
}

// ---------------- GEMM2 (R6): 64x128 tile, 4 waves, 24KB buffer
__global__ __launch_bounds__(256, 4) void gemm_proj_bf16(
    const unsigned short* __restrict__ A, const unsigned short* __restrict__ Bt,
    const float* __restrict__ bias, float* __restrict__ out)
{
    __shared__ unsigned short As[64*64];
    __shared__ unsigned short Bs[128*64];
    const int tid = threadIdx.x;
    const int id = blockIdx.x;              // 768 blocks = 3/CU exact
    const int swz = (id & 7) * 96 + (id >> 3);
    const int n0 = (swz % 6) * 128, m0 = (swz / 6) * 64;

    const int lane = tid & 63, w = tid >> 6;
    const int l15 = lane & 15, lhi = lane >> 4;
    const int wm = w >> 1, wn = w & 1;
    const int wb = tid & 192;

    const unsigned short* Ab = A  + (size_t)m0 * 768;
    const unsigned short* Bb = Bt + (size_t)n0 * 768;

    f32x4_t acc[2][4] = {};

    #pragma unroll 1
    for (int t = 0; t < 12; ++t) {
        STAGE_TILE(As, Ab, t*64, 2, 256)
        STAGE_TILE(Bs, Bb, t*64, 4, 256)
        WAIT0; BAR;
        COMPUTE_P(As, Bs)
        BAR;
    }

    #pragma unroll
    for (int n = 0; n < 4; ++n) {
        const int gcol = n0 + wn*64 + n*16 + l15;
        const float bv = bias[gcol];
        #pragma unroll
        for (int m = 0; m < 2; ++m) {
            const int grow_base = m0 + wm*32 + m*16 + lhi*4;
            #pragma unroll
            for (int reg = 0; reg < 4; ++reg)
                out[(size_t)(grow_base + reg)*768 + gcol] = acc[m][n][reg] + bv;
        }
    }
}

extern "C" void kernel_launch(void* const* d_in, const int* in_sizes, int n_in,
                              void* d_out, int out_size, void* d_ws, size_t ws_size,
                              hipStream_t stream) {
    const float* x     = (const float*)d_in[0];
    const float* Wqkv  = (const float*)d_in[1];
    const float* bqkv  = (const float*)d_in[2];
    const float* Wproj = (const float*)d_in[3];
    const float* bproj = (const float*)d_in[4];
    float* out = (float*)d_out;
    unsigned short* ws = (unsigned short*)d_ws;

    unsigned short* xf    = ws;                       // 6291456  (frag layout)
    unsigned short* obuf  = ws;                       // alias (xf dead after gemm_qkv)
    unsigned short* wf    = ws + 6291456u;            // 1769472  (frag layout)
    unsigned short* wpt   = ws + 8060928u;            // 589824
    unsigned short* qb    = ws + 8650752u;            // 6291456
    unsigned short* kb    = ws + 14942208u;           // 6291456
    unsigned short* vTb   = ws + 21233664u;           // 6291456

    convert_x_frag<<<3072, 256, 0, stream>>>(x, xf);
    frag_wq       <<<864,  256, 0, stream>>>(Wqkv, wf);
    transpose_cvt <<<dim3(24, 24), 256, 0, stream>>>(Wproj, wpt, 768, 768);
    gemm_qkv_bf16 <<<1152, 256, 0, stream>>>(xf, wf, bqkv, qb, kb, vTb);
    attn2         <<<1536, 256, 0, stream>>>(qb, kb, vTb, obuf);
    gemm_proj_bf16<<<768,  256, 0, stream>>>(obuf, wpt, bproj, out);
}

// Round 12
// 130.078 us; speedup vs baseline: 1.0831x; 1.0804x over previous
//
#include <hip/hip_runtime.h>

// B=8, N=1024, C=768, H=12, D=64.
// Pipeline: [convert x -> bf16] [transpose+convert Wqkv, Wproj -> Bt bf16]
//           [gemm_qkv R12: PROJ-STRUCTURE CLONE — 64x128 tile, 24KB LDS,
//            4 blocks/CU, L2-aware XCD swizzle; q(scaled),k row; v transposed]
//           [attn R6: exp-softmax, single-buffer K/Vt + reg-staged prefetch]
//           [gemm_proj R6: 64x128/4w -> f32 out + bias]
// R12: accounting showed proj's naive 2-phase at 64x128/24KB/4-blocks-per-CU
//      runs ~2x qkv's efficiency. Clone it for qkv; swizzle keeps per-XCD
//      hot set (A-slice 1.5MB + one B-panel) under 4MB L2.

typedef short  bf16x8_t __attribute__((ext_vector_type(8)));
typedef float  f32x4_t  __attribute__((ext_vector_type(4)));

static __device__ __forceinline__ unsigned short f2bf(float f) {
    union { float f; unsigned u; } v; v.f = f;
    unsigned r = v.u + 0x7fffu + ((v.u >> 16) & 1u);   // RNE
    return (unsigned short)(r >> 16);
}

typedef __attribute__((address_space(1))) const unsigned gas_u32;
typedef __attribute__((address_space(3))) unsigned las_u32;
static __device__ __forceinline__ void gload16(const void* g, void* l) {
    __builtin_amdgcn_global_load_lds((gas_u32*)g, (las_u32*)l, 16, 0, 0);
}

#define WAIT0 asm volatile("s_waitcnt vmcnt(0)" ::: "memory")
#define BAR   __builtin_amdgcn_s_barrier()

// Stage a [ROWS x 64] bf16 tile from row-major src (stride 768 u16) into
// linear LDS via gload_lds, chunk-XOR swizzle applied on the GLOBAL source.
#define STAGE_TILE(DST, SRC, K0, NP, NT)                                   \
    _Pragma("unroll")                                                      \
    for (int p_ = 0; p_ < NP; ++p_) {                                      \
        const int base_ = p_*NT + wb;                                      \
        const int i_ = base_ + lane;                                       \
        const int row_ = i_ >> 3;                                          \
        const int cb_ = ((i_ & 7) ^ (row_ & 7)) * 8;                       \
        gload16((SRC) + (size_t)row_*768 + (K0) + cb_, &(DST)[base_*8]);   \
    }

// 2(m) x 4(n) frag compute, wave rows wm*32, cols wn*64 (64x128 tile).
#define COMPUTE_P(AS, BS)                                                  \
    {                                                                      \
        bf16x8_t a_[2][2], b_[2][4];                                       \
        _Pragma("unroll")                                                  \
        for (int ks_ = 0; ks_ < 2; ++ks_) {                                \
            _Pragma("unroll")                                              \
            for (int m_ = 0; m_ < 2; ++m_) {                               \
                const int ra_ = wm*32 + m_*16 + l15;                       \
                a_[ks_][m_] = *(const bf16x8_t*)&(AS)[ra_*64 + ((ks_*4 + lhi) ^ (ra_ & 7))*8]; \
            }                                                              \
            _Pragma("unroll")                                              \
            for (int n_ = 0; n_ < 4; ++n_) {                               \
                const int rb_ = wn*64 + n_*16 + l15;                       \
                b_[ks_][n_] = *(const bf16x8_t*)&(BS)[rb_*64 + ((ks_*4 + lhi) ^ (rb_ & 7))*8]; \
            }                                                              \
        }                                                                  \
        _Pragma("unroll")                                                  \
        for (int m_ = 0; m_ < 2; ++m_)                                     \
            _Pragma("unroll")                                              \
            for (int n_ = 0; n_ < 4; ++n_) {                               \
                acc[m_][n_] = __builtin_amdgcn_mfma_f32_16x16x32_bf16(a_[0][m_], b_[0][n_], acc[m_][n_], 0, 0, 0); \
                acc[m_][n_] = __builtin_amdgcn_mfma_f32_16x16x32_bf16(a_[1][m_], b_[1][n_], acc[m_][n_], 0, 0, 0); \
            }                                                              \
    }

// ---------------- pre-pass: x f32 -> bf16 (same layout)
__global__ __launch_bounds__(256) void convert_x(
    const float* __restrict__ src, unsigned short* __restrict__ dst)
{
    const int i = blockIdx.x * 256 + threadIdx.x;
    const float4 v = ((const float4*)src)[i];
    ushort4 o; o.x = f2bf(v.x); o.y = f2bf(v.y); o.z = f2bf(v.z); o.w = f2bf(v.w);
    ((ushort4*)dst)[i] = o;
}

// ---------------- pre-pass: W [R][C] f32 -> Wt [C][R] bf16
__global__ __launch_bounds__(256) void transpose_cvt(
    const float* __restrict__ src, unsigned short* __restrict__ dst, int R, int C)
{
    __shared__ unsigned short tile[32][33];
    const int tx = threadIdx.x & 31, ty = threadIdx.x >> 5;
    const int bx = blockIdx.x, by = blockIdx.y;
    #pragma unroll
    for (int j = 0; j < 32; j += 8)
        tile[ty + j][tx] = f2bf(src[(size_t)(by*32 + ty + j) * C + bx*32 + tx]);
    __syncthreads();
    #pragma unroll
    for (int j = 0; j < 32; j += 8)
        dst[(size_t)(bx*32 + ty + j) * R + by*32 + tx] = tile[tx][ty + j];
}

// ---------------- GEMM1 (R12): 64x128 tile, 4 waves, 24KB buffer, 4/CU
__global__ __launch_bounds__(256, 4) void gemm_qkv_bf16(
    const unsigned short* __restrict__ A, const unsigned short* __restrict__ Bt,
    const float* __restrict__ bias,
    unsigned short* __restrict__ q, unsigned short* __restrict__ kO,
    unsigned short* __restrict__ vT)
{
    __shared__ unsigned short As[64*64];    // 8KB
    __shared__ unsigned short Bs[128*64];   // 16KB
    const int tid = threadIdx.x;
    const int id = blockIdx.x;              // 2304 blocks, 2304%8==0
    // L2-aware swizzle: per XCD, A-slice interleaved (stays hot, 1.5MB),
    // nb slow-varying (one 0.4MB B-panel hot at a time).
    const int xcd = id & 7, r = id >> 3;    // r 0..287
    const int nb = r >> 4;                  // 0..17 (slow)
    const int mb = (r & 15) * 8 + xcd;      // 0..127 (bijective)
    const int n0 = nb * 128, m0 = mb * 64;

    const int lane = tid & 63, w = tid >> 6;
    const int l15 = lane & 15, lhi = lane >> 4;
    const int wm = w >> 1, wn = w & 1;      // 2x2 wave grid
    const int wb = tid & 192;

    const unsigned short* Ab = A  + (size_t)m0 * 768;
    const unsigned short* Bb = Bt + (size_t)n0 * 768;

    f32x4_t acc[2][4] = {};

    #pragma unroll 1
    for (int t = 0; t < 12; ++t) {
        STAGE_TILE(As, Ab, t*64, 2, 256)
        STAGE_TILE(Bs, Bb, t*64, 4, 256)
        WAIT0; BAR;
        COMPUTE_P(As, Bs)
        BAR;
    }

    // epilogue: qkv scatter. kk block-uniform (128 | 768).
    #pragma unroll
    for (int n = 0; n < 4; ++n) {
        const int gcol = n0 + wn*64 + n*16 + l15;         // 0..2303
        const int kk = gcol / 768;                        // 0=q,1=k,2=v
        const int rr = gcol - kk*768;
        const int h  = rr >> 6, d = rr & 63;
        const float bv = bias[gcol];
        const float sc = (kk == 0) ? 0.125f : 1.0f;
        #pragma unroll
        for (int m = 0; m < 2; ++m) {
            const int grow_base = m0 + wm*32 + m*16 + lhi*4;
            #pragma unroll
            for (int reg = 0; reg < 4; ++reg) {
                const int grow = grow_base + reg;         // b*1024+seq
                const int bb = grow >> 10, seq = grow & 1023;
                const unsigned short ov = f2bf((acc[m][n][reg] + bv) * sc);
                const size_t bh = (size_t)bb*12 + h;
                if (kk == 0)      q [ (bh*1024 + seq)*64 + d ] = ov;
                else if (kk == 1) kO[ (bh*1024 + seq)*64 + d ] = ov;
                else              vT[ (bh*64 + d)*1024 + seq ] = ov;
            }
        }
    }
}

// ---------------- Attention (R6): single-buffer K/Vt + reg-staged prefetch
__global__ __launch_bounds__(256, 5) void attn2(
    const unsigned short* __restrict__ q, const unsigned short* __restrict__ k,
    const unsigned short* __restrict__ vT, unsigned short* __restrict__ obuf)
{
    __shared__ unsigned short Ks[64 * 72];
    __shared__ unsigned short Vs[64 * 72];
    __shared__ unsigned short P[4][16 * 72];
    const int tid = threadIdx.x;
    const int id = blockIdx.x;                 // 1536 blocks
    const int swz = (id & 7) * 192 + (id >> 3);
    const int qt = swz & 15, bh = swz >> 4;

    const int lane = tid & 63, w = tid >> 6;
    const int l15 = lane & 15, lhi = lane >> 4;
    const unsigned short* qp = q  + (size_t)bh * 65536;
    const unsigned short* kp = k  + (size_t)bh * 65536;
    const unsigned short* vp = vT + (size_t)bh * 65536;  // [64 d][1024 n]

    bf16x8_t qf[2];
    const int qrow = qt*64 + w*16 + l15;
    #pragma unroll
    for (int ks = 0; ks < 2; ++ks)
        qf[ks] = *(const bf16x8_t*)(qp + (size_t)qrow*64 + ks*32 + lhi*8);

    f32x4_t acco[4] = {};
    float lsum[4] = {0.f, 0.f, 0.f, 0.f};
    unsigned short* Pw = P[w];

    bf16x8_t kr[2], vr[2];
    #pragma unroll
    for (int p = 0; p < 2; ++p) {
        const int idx = p*256 + tid;
        const int r8 = idx >> 3, cb = (idx & 7) * 8;
        kr[p] = *(const bf16x8_t*)(kp + (size_t)r8*64 + cb);
        vr[p] = *(const bf16x8_t*)(vp + (size_t)r8*1024 + cb);
    }
    #pragma unroll
    for (int p = 0; p < 2; ++p) {
        const int idx = p*256 + tid;
        const int r8 = idx >> 3, cb = (idx & 7) * 8;
        *(bf16x8_t*)&Ks[r8*72 + cb] = kr[p];
        *(bf16x8_t*)&Vs[r8*72 + cb] = vr[p];
    }

    for (int kt = 0; kt < 16; ++kt) {
        __syncthreads();
        if (kt < 15) {
            #pragma unroll
            for (int p = 0; p < 2; ++p) {
                const int idx = p*256 + tid;
                const int r8 = idx >> 3, cb = (idx & 7) * 8;
                kr[p] = *(const bf16x8_t*)(kp + (size_t)((kt+1)*64 + r8)*64 + cb);
                vr[p] = *(const bf16x8_t*)(vp + (size_t)r8*1024 + (kt+1)*64 + cb);
            }
        }

        f32x4_t accs[4] = {};
        __builtin_amdgcn_s_setprio(1);
        #pragma unroll
        for (int c = 0; c < 4; ++c)
            #pragma unroll
            for (int ks = 0; ks < 2; ++ks) {
                bf16x8_t kf = *(const bf16x8_t*)&Ks[(c*16 + l15)*72 + ks*32 + lhi*8];
                accs[c] = __builtin_amdgcn_mfma_f32_16x16x32_bf16(qf[ks], kf, accs[c], 0, 0, 0);
            }
        __builtin_amdgcn_s_setprio(0);

        #pragma unroll
        for (int c = 0; c < 4; ++c)
            #pragma unroll
            for (int r = 0; r < 4; ++r) {
                const float pv = __expf(accs[c][r]);
                lsum[r] += pv;
                Pw[(lhi*4 + r)*72 + c*16 + l15] = f2bf(pv);
            }

        bf16x8_t pf[2];
        #pragma unroll
        for (int ks = 0; ks < 2; ++ks)
            pf[ks] = *(const bf16x8_t*)&Pw[l15*72 + ks*32 + lhi*8];
        __builtin_amdgcn_s_setprio(1);
        #pragma unroll
        for (int n = 0; n < 4; ++n)
            #pragma unroll
            for (int ks = 0; ks < 2; ++ks) {
                bf16x8_t vf = *(const bf16x8_t*)&Vs[(n*16 + l15)*72 + ks*32 + lhi*8];
                acco[n] = __builtin_amdgcn_mfma_f32_16x16x32_bf16(pf[ks], vf, acco[n], 0, 0, 0);
            }
        __builtin_amdgcn_s_setprio(0);

        __syncthreads();
        if (kt < 15) {
            #pragma unroll
            for (int p = 0; p < 2; ++p) {
                const int idx = p*256 + tid;
                const int r8 = idx >> 3, cb = (idx & 7) * 8;
                *(bf16x8_t*)&Ks[r8*72 + cb] = kr[p];
                *(bf16x8_t*)&Vs[r8*72 + cb] = vr[p];
            }
        }
    }

    #pragma unroll
    for (int r = 0; r < 4; ++r)
        #pragma unroll
        for (int off = 1; off <= 8; off <<= 1)
            lsum[r] += __shfl_xor(lsum[r], off, 64);

    const int b = bh / 12, h = bh % 12;
    #pragma unroll
    for (int n = 0; n < 4; ++n)
        #pragma unroll
        for (int r = 0; r < 4; ++r) {
            const int seq = qt*64 + w*16 + lhi*4 + r;
            obuf[((size_t)(b*1024 + seq))*768 + h*64 + n*16 + l15] = f2bf(acco[n][r] / lsum[r]);
        }
}

// ---------------- GEMM2 (R6): 64x128 tile, 4 waves, 24KB buffer
__global__ __launch_bounds__(256, 4) void gemm_proj_bf16(
    const unsigned short* __restrict__ A, const unsigned short* __restrict__ Bt,
    const float* __restrict__ bias, float* __restrict__ out)
{
    __shared__ unsigned short As[64*64];
    __shared__ unsigned short Bs[128*64];
    const int tid = threadIdx.x;
    const int id = blockIdx.x;              // 768 blocks
    const int swz = (id & 7) * 96 + (id >> 3);
    const int n0 = (swz % 6) * 128, m0 = (swz / 6) * 64;

    const int lane = tid & 63, w = tid >> 6;
    const int l15 = lane & 15, lhi = lane >> 4;
    const int wm = w >> 1, wn = w & 1;
    const int wb = tid & 192;

    const unsigned short* Ab = A  + (size_t)m0 * 768;
    const unsigned short* Bb = Bt + (size_t)n0 * 768;

    f32x4_t acc[2][4] = {};

    #pragma unroll 1
    for (int t = 0; t < 12; ++t) {
        STAGE_TILE(As, Ab, t*64, 2, 256)
        STAGE_TILE(Bs, Bb, t*64, 4, 256)
        WAIT0; BAR;
        COMPUTE_P(As, Bs)
        BAR;
    }

    #pragma unroll
    for (int n = 0; n < 4; ++n) {
        const int gcol = n0 + wn*64 + n*16 + l15;
        const float bv = bias[gcol];
        #pragma unroll
        for (int m = 0; m < 2; ++m) {
            const int grow_base = m0 + wm*32 + m*16 + lhi*4;
            #pragma unroll
            for (int reg = 0; reg < 4; ++reg)
                out[(size_t)(grow_base + reg)*768 + gcol] = acc[m][n][reg] + bv;
        }
    }
}

extern "C" void kernel_launch(void* const* d_in, const int* in_sizes, int n_in,
                              void* d_out, int out_size, void* d_ws, size_t ws_size,
                              hipStream_t stream) {
    const float* x     = (const float*)d_in[0];
    const float* Wqkv  = (const float*)d_in[1];
    const float* bqkv  = (const float*)d_in[2];
    const float* Wproj = (const float*)d_in[3];
    const float* bproj = (const float*)d_in[4];
    float* out = (float*)d_out;
    unsigned short* ws = (unsigned short*)d_ws;

    unsigned short* xb    = ws;                       // 6291456
    unsigned short* obuf  = ws;                       // alias (xb dead after gemm_qkv)
    unsigned short* wqt   = ws + 6291456u;            // 1769472
    unsigned short* wpt   = ws + 8060928u;            // 589824
    unsigned short* qb    = ws + 8650752u;            // 6291456
    unsigned short* kb    = ws + 14942208u;           // 6291456
    unsigned short* vTb   = ws + 21233664u;           // 6291456

    convert_x     <<<6144, 256, 0, stream>>>(x, xb);
    transpose_cvt <<<dim3(72, 24), 256, 0, stream>>>(Wqkv, wqt, 768, 2304);
    transpose_cvt <<<dim3(24, 24), 256, 0, stream>>>(Wproj, wpt, 768, 768);
    gemm_qkv_bf16 <<<2304, 256, 0, stream>>>(xb, wqt, bqkv, qb, kb, vTb);
    attn2         <<<1536, 256, 0, stream>>>(qb, kb, vTb, obuf);
    gemm_proj_bf16<<<768,  256, 0, stream>>>(obuf, wpt, bproj, out);
}

// Round 13
// 125.519 us; speedup vs baseline: 1.1224x; 1.0363x over previous
//
#include <hip/hip_runtime.h>

// B=8, N=1024, C=768, H=12, D=64.
// Pipeline: [convert x -> bf16] [transpose+convert Wqkv, Wproj -> Bt bf16]
//           [gemm_qkv R12: 64x128 tile, 24KB LDS, L2-aware XCD swizzle]
//           [attn R13: 8-wave QBLK=128 — K/V staged once per 128 q-rows,
//            768 blocks = 3/CU exact, T14 reg prefetch kept]
//           [gemm_proj R6: 64x128/4w -> f32 out + bias]
// R13: attn staging amortization (global staging work halved, zero dispatch
//      tail) + launch_bounds 6 blocks/CU on both GEMMs for backfill.

typedef short  bf16x8_t __attribute__((ext_vector_type(8)));
typedef float  f32x4_t  __attribute__((ext_vector_type(4)));

static __device__ __forceinline__ unsigned short f2bf(float f) {
    union { float f; unsigned u; } v; v.f = f;
    unsigned r = v.u + 0x7fffu + ((v.u >> 16) & 1u);   // RNE
    return (unsigned short)(r >> 16);
}

typedef __attribute__((address_space(1))) const unsigned gas_u32;
typedef __attribute__((address_space(3))) unsigned las_u32;
static __device__ __forceinline__ void gload16(const void* g, void* l) {
    __builtin_amdgcn_global_load_lds((gas_u32*)g, (las_u32*)l, 16, 0, 0);
}

#define WAIT0 asm volatile("s_waitcnt vmcnt(0)" ::: "memory")
#define BAR   __builtin_amdgcn_s_barrier()

// Stage a [ROWS x 64] bf16 tile from row-major src (stride 768 u16) into
// linear LDS via gload_lds, chunk-XOR swizzle applied on the GLOBAL source.
#define STAGE_TILE(DST, SRC, K0, NP, NT)                                   \
    _Pragma("unroll")                                                      \
    for (int p_ = 0; p_ < NP; ++p_) {                                      \
        const int base_ = p_*NT + wb;                                      \
        const int i_ = base_ + lane;                                       \
        const int row_ = i_ >> 3;                                          \
        const int cb_ = ((i_ & 7) ^ (row_ & 7)) * 8;                       \
        gload16((SRC) + (size_t)row_*768 + (K0) + cb_, &(DST)[base_*8]);   \
    }

// 2(m) x 4(n) frag compute, wave rows wm*32, cols wn*64 (64x128 tile).
#define COMPUTE_P(AS, BS)                                                  \
    {                                                                      \
        bf16x8_t a_[2][2], b_[2][4];                                       \
        _Pragma("unroll")                                                  \
        for (int ks_ = 0; ks_ < 2; ++ks_) {                                \
            _Pragma("unroll")                                              \
            for (int m_ = 0; m_ < 2; ++m_) {                               \
                const int ra_ = wm*32 + m_*16 + l15;                       \
                a_[ks_][m_] = *(const bf16x8_t*)&(AS)[ra_*64 + ((ks_*4 + lhi) ^ (ra_ & 7))*8]; \
            }                                                              \
            _Pragma("unroll")                                              \
            for (int n_ = 0; n_ < 4; ++n_) {                               \
                const int rb_ = wn*64 + n_*16 + l15;                       \
                b_[ks_][n_] = *(const bf16x8_t*)&(BS)[rb_*64 + ((ks_*4 + lhi) ^ (rb_ & 7))*8]; \
            }                                                              \
        }                                                                  \
        _Pragma("unroll")                                                  \
        for (int m_ = 0; m_ < 2; ++m_)                                     \
            _Pragma("unroll")                                              \
            for (int n_ = 0; n_ < 4; ++n_) {                               \
                acc[m_][n_] = __builtin_amdgcn_mfma_f32_16x16x32_bf16(a_[0][m_], b_[0][n_], acc[m_][n_], 0, 0, 0); \
                acc[m_][n_] = __builtin_amdgcn_mfma_f32_16x16x32_bf16(a_[1][m_], b_[1][n_], acc[m_][n_], 0, 0, 0); \
            }                                                              \
    }

// ---------------- pre-pass: x f32 -> bf16 (same layout)
__global__ __launch_bounds__(256) void convert_x(
    const float* __restrict__ src, unsigned short* __restrict__ dst)
{
    const int i = blockIdx.x * 256 + threadIdx.x;
    const float4 v = ((const float4*)src)[i];
    ushort4 o; o.x = f2bf(v.x); o.y = f2bf(v.y); o.z = f2bf(v.z); o.w = f2bf(v.w);
    ((ushort4*)dst)[i] = o;
}

// ---------------- pre-pass: W [R][C] f32 -> Wt [C][R] bf16
__global__ __launch_bounds__(256) void transpose_cvt(
    const float* __restrict__ src, unsigned short* __restrict__ dst, int R, int C)
{
    __shared__ unsigned short tile[32][33];
    const int tx = threadIdx.x & 31, ty = threadIdx.x >> 5;
    const int bx = blockIdx.x, by = blockIdx.y;
    #pragma unroll
    for (int j = 0; j < 32; j += 8)
        tile[ty + j][tx] = f2bf(src[(size_t)(by*32 + ty + j) * C + bx*32 + tx]);
    __syncthreads();
    #pragma unroll
    for (int j = 0; j < 32; j += 8)
        dst[(size_t)(bx*32 + ty + j) * R + by*32 + tx] = tile[tx][ty + j];
}

// ---------------- GEMM1 (R12 + 6/CU): 64x128 tile, 4 waves, 24KB buffer
__global__ __launch_bounds__(256, 6) void gemm_qkv_bf16(
    const unsigned short* __restrict__ A, const unsigned short* __restrict__ Bt,
    const float* __restrict__ bias,
    unsigned short* __restrict__ q, unsigned short* __restrict__ kO,
    unsigned short* __restrict__ vT)
{
    __shared__ unsigned short As[64*64];    // 8KB
    __shared__ unsigned short Bs[128*64];   // 16KB
    const int tid = threadIdx.x;
    const int id = blockIdx.x;              // 2304 blocks, 2304%8==0
    const int xcd = id & 7, r = id >> 3;    // r 0..287
    const int nb = r >> 4;                  // 0..17 (slow)
    const int mb = (r & 15) * 8 + xcd;      // 0..127 (bijective)
    const int n0 = nb * 128, m0 = mb * 64;

    const int lane = tid & 63, w = tid >> 6;
    const int l15 = lane & 15, lhi = lane >> 4;
    const int wm = w >> 1, wn = w & 1;      // 2x2 wave grid
    const int wb = tid & 192;

    const unsigned short* Ab = A  + (size_t)m0 * 768;
    const unsigned short* Bb = Bt + (size_t)n0 * 768;

    f32x4_t acc[2][4] = {};

    #pragma unroll 1
    for (int t = 0; t < 12; ++t) {
        STAGE_TILE(As, Ab, t*64, 2, 256)
        STAGE_TILE(Bs, Bb, t*64, 4, 256)
        WAIT0; BAR;
        COMPUTE_P(As, Bs)
        BAR;
    }

    // epilogue: qkv scatter. kk block-uniform (128 | 768).
    #pragma unroll
    for (int n = 0; n < 4; ++n) {
        const int gcol = n0 + wn*64 + n*16 + l15;         // 0..2303
        const int kk = gcol / 768;                        // 0=q,1=k,2=v
        const int rr = gcol - kk*768;
        const int h  = rr >> 6, d = rr & 63;
        const float bv = bias[gcol];
        const float sc = (kk == 0) ? 0.125f : 1.0f;
        #pragma unroll
        for (int m = 0; m < 2; ++m) {
            const int grow_base = m0 + wm*32 + m*16 + lhi*4;
            #pragma unroll
            for (int reg = 0; reg < 4; ++reg) {
                const int grow = grow_base + reg;         // b*1024+seq
                const int bb = grow >> 10, seq = grow & 1023;
                const unsigned short ov = f2bf((acc[m][n][reg] + bv) * sc);
                const size_t bh = (size_t)bb*12 + h;
                if (kk == 0)      q [ (bh*1024 + seq)*64 + d ] = ov;
                else if (kk == 1) kO[ (bh*1024 + seq)*64 + d ] = ov;
                else              vT[ (bh*64 + d)*1024 + seq ] = ov;
            }
        }
    }
}

// ---------------- Attention (R13): 8 waves, QBLK=128, shared K/V staging
__global__ __launch_bounds__(512, 6) void attn2(
    const unsigned short* __restrict__ q, const unsigned short* __restrict__ k,
    const unsigned short* __restrict__ vT, unsigned short* __restrict__ obuf)
{
    __shared__ unsigned short Ks[64 * 72];
    __shared__ unsigned short Vs[64 * 72];
    __shared__ unsigned short P[8][16 * 72];   // 36864 B total
    const int tid = threadIdx.x;
    const int id = blockIdx.x;                 // 768 blocks, 768%8==0
    const int swz = (id & 7) * 96 + (id >> 3);
    const int qt = swz & 7, bh = swz >> 3;     // 8 q-tiles of 128, 96 bh

    const int lane = tid & 63, w = tid >> 6;   // w 0..7
    const int l15 = lane & 15, lhi = lane >> 4;
    const unsigned short* qp = q  + (size_t)bh * 65536;
    const unsigned short* kp = k  + (size_t)bh * 65536;
    const unsigned short* vp = vT + (size_t)bh * 65536;  // [64 d][1024 n]

    bf16x8_t qf[2];
    const int qrow = qt*128 + w*16 + l15;
    #pragma unroll
    for (int ks = 0; ks < 2; ++ks)
        qf[ks] = *(const bf16x8_t*)(qp + (size_t)qrow*64 + ks*32 + lhi*8);

    f32x4_t acco[4] = {};
    float lsum[4] = {0.f, 0.f, 0.f, 0.f};
    unsigned short* Pw = P[w];

    // staging: 512 threads cover the full 64x64 tile in one chunk each
    const int r8 = tid >> 3, cb = (tid & 7) * 8;
    bf16x8_t kr, vr;
    kr = *(const bf16x8_t*)(kp + (size_t)r8*64 + cb);
    vr = *(const bf16x8_t*)(vp + (size_t)r8*1024 + cb);
    *(bf16x8_t*)&Ks[r8*72 + cb] = kr;
    *(bf16x8_t*)&Vs[r8*72 + cb] = vr;

    for (int kt = 0; kt < 16; ++kt) {
        __syncthreads();                       // staged tile visible to 8 waves
        if (kt < 15) {                         // T14: issue next-tile loads now
            kr = *(const bf16x8_t*)(kp + (size_t)((kt+1)*64 + r8)*64 + cb);
            vr = *(const bf16x8_t*)(vp + (size_t)r8*1024 + (kt+1)*64 + cb);
        }

        f32x4_t accs[4] = {};
        __builtin_amdgcn_s_setprio(1);
        #pragma unroll
        for (int c = 0; c < 4; ++c)
            #pragma unroll
            for (int ks = 0; ks < 2; ++ks) {
                bf16x8_t kf = *(const bf16x8_t*)&Ks[(c*16 + l15)*72 + ks*32 + lhi*8];
                accs[c] = __builtin_amdgcn_mfma_f32_16x16x32_bf16(qf[ks], kf, accs[c], 0, 0, 0);
            }
        __builtin_amdgcn_s_setprio(0);

        #pragma unroll
        for (int c = 0; c < 4; ++c)
            #pragma unroll
            for (int r = 0; r < 4; ++r) {
                const float pv = __expf(accs[c][r]);
                lsum[r] += pv;
                Pw[(lhi*4 + r)*72 + c*16 + l15] = f2bf(pv);
            }

        bf16x8_t pf[2];
        #pragma unroll
        for (int ks = 0; ks < 2; ++ks)
            pf[ks] = *(const bf16x8_t*)&Pw[l15*72 + ks*32 + lhi*8];
        __builtin_amdgcn_s_setprio(1);
        #pragma unroll
        for (int n = 0; n < 4; ++n)
            #pragma unroll
            for (int ks = 0; ks < 2; ++ks) {
                bf16x8_t vf = *(const bf16x8_t*)&Vs[(n*16 + l15)*72 + ks*32 + lhi*8];
                acco[n] = __builtin_amdgcn_mfma_f32_16x16x32_bf16(pf[ks], vf, acco[n], 0, 0, 0);
            }
        __builtin_amdgcn_s_setprio(0);

        __syncthreads();                       // all 8 waves done reading Ks/Vs
        if (kt < 15) {                         // write-late into single buffer
            *(bf16x8_t*)&Ks[r8*72 + cb] = kr;
            *(bf16x8_t*)&Vs[r8*72 + cb] = vr;
        }
    }

    #pragma unroll
    for (int r = 0; r < 4; ++r)
        #pragma unroll
        for (int off = 1; off <= 8; off <<= 1)
            lsum[r] += __shfl_xor(lsum[r], off, 64);

    const int b = bh / 12, h = bh % 12;
    #pragma unroll
    for (int n = 0; n < 4; ++n)
        #pragma unroll
        for (int r = 0; r < 4; ++r) {
            const int seq = qt*128 + w*16 + lhi*4 + r;
            obuf[((size_t)(b*1024 + seq))*768 + h*64 + n*16 + l15] = f2bf(acco[n][r] / lsum[r]);
        }
}

// ---------------- GEMM2 (R6 + 6/CU): 64x128 tile, 4 waves, 24KB buffer
__global__ __launch_bounds__(256, 6) void gemm_proj_bf16(
    const unsigned short* __restrict__ A, const unsigned short* __restrict__ Bt,
    const float* __restrict__ bias, float* __restrict__ out)
{
    __shared__ unsigned short As[64*64];
    __shared__ unsigned short Bs[128*64];
    const int tid = threadIdx.x;
    const int id = blockIdx.x;              // 768 blocks
    const int swz = (id & 7) * 96 + (id >> 3);
    const int n0 = (swz % 6) * 128, m0 = (swz / 6) * 64;

    const int lane = tid & 63, w = tid >> 6;
    const int l15 = lane & 15, lhi = lane >> 4;
    const int wm = w >> 1, wn = w & 1;
    const int wb = tid & 192;

    const unsigned short* Ab = A  + (size_t)m0 * 768;
    const unsigned short* Bb = Bt + (size_t)n0 * 768;

    f32x4_t acc[2][4] = {};

    #pragma unroll 1
    for (int t = 0; t < 12; ++t) {
        STAGE_TILE(As, Ab, t*64, 2, 256)
        STAGE_TILE(Bs, Bb, t*64, 4, 256)
        WAIT0; BAR;
        COMPUTE_P(As, Bs)
        BAR;
    }

    #pragma unroll
    for (int n = 0; n < 4; ++n) {
        const int gcol = n0 + wn*64 + n*16 + l15;
        const float bv = bias[gcol];
        #pragma unroll
        for (int m = 0; m < 2; ++m) {
            const int grow_base = m0 + wm*32 + m*16 + lhi*4;
            #pragma unroll
            for (int reg = 0; reg < 4; ++reg)
                out[(size_t)(grow_base + reg)*768 + gcol] = acc[m][n][reg] + bv;
        }
    }
}

extern "C" void kernel_launch(void* const* d_in, const int* in_sizes, int n_in,
                              void* d_out, int out_size, void* d_ws, size_t ws_size,
                              hipStream_t stream) {
    const float* x     = (const float*)d_in[0];
    const float* Wqkv  = (const float*)d_in[1];
    const float* bqkv  = (const float*)d_in[2];
    const float* Wproj = (const float*)d_in[3];
    const float* bproj = (const float*)d_in[4];
    float* out = (float*)d_out;
    unsigned short* ws = (unsigned short*)d_ws;

    unsigned short* xb    = ws;                       // 6291456
    unsigned short* obuf  = ws;                       // alias (xb dead after gemm_qkv)
    unsigned short* wqt   = ws + 6291456u;            // 1769472
    unsigned short* wpt   = ws + 8060928u;            // 589824
    unsigned short* qb    = ws + 8650752u;            // 6291456
    unsigned short* kb    = ws + 14942208u;           // 6291456
    unsigned short* vTb   = ws + 21233664u;           // 6291456

    convert_x     <<<6144, 256, 0, stream>>>(x, xb);
    transpose_cvt <<<dim3(72, 24), 256, 0, stream>>>(Wqkv, wqt, 768, 2304);
    transpose_cvt <<<dim3(24, 24), 256, 0, stream>>>(Wproj, wpt, 768, 768);
    gemm_qkv_bf16 <<<2304, 256, 0, stream>>>(xb, wqt, bqkv, qb, kb, vTb);
    attn2         <<<768,  512, 0, stream>>>(qb, kb, vTb, obuf);
    gemm_proj_bf16<<<768,  256, 0, stream>>>(obuf, wpt, bproj, out);
}

// Round 14
// 123.297 us; speedup vs baseline: 1.1426x; 1.0180x over previous
//
#include <hip/hip_runtime.h>

// B=8, N=1024, C=768, H=12, D=64.
// Pipeline: [convert x -> bf16] [transpose+convert Wqkv, Wproj -> Bt bf16]
//           [gemm_qkv R14: 128Mx64N tile (B-panel 96KB), XCD-pinned mb,
//            nb-grouped-by-8 -> per-XCD L2 set ~3.8MB < 4MB]
//           [attn R13: 8-wave QBLK=128, single-buffer K/Vt + reg prefetch]
//           [gemm_proj R6: 64x128/4w -> f32 out + bias]
// R14: qkv L2-thrash fix. R13's 64x128 qkv held ~6.3MB hot per XCD (12
//      B-panels x 0.4MB + A 1.5MB) -> thrash; proj's 2.7MB fits and runs
//      1.7x faster per block. Swapping tile aspect shrinks B-panels to
//      96KB and pins an 8-panel A-slice per XCD.

typedef short  bf16x8_t __attribute__((ext_vector_type(8)));
typedef float  f32x4_t  __attribute__((ext_vector_type(4)));

static __device__ __forceinline__ unsigned short f2bf(float f) {
    union { float f; unsigned u; } v; v.f = f;
    unsigned r = v.u + 0x7fffu + ((v.u >> 16) & 1u);   // RNE
    return (unsigned short)(r >> 16);
}

typedef __attribute__((address_space(1))) const unsigned gas_u32;
typedef __attribute__((address_space(3))) unsigned las_u32;
static __device__ __forceinline__ void gload16(const void* g, void* l) {
    __builtin_amdgcn_global_load_lds((gas_u32*)g, (las_u32*)l, 16, 0, 0);
}

#define WAIT0 asm volatile("s_waitcnt vmcnt(0)" ::: "memory")
#define BAR   __builtin_amdgcn_s_barrier()

// Stage a [ROWS x 64] bf16 tile from row-major src (stride 768 u16) into
// linear LDS via gload_lds, chunk-XOR swizzle applied on the GLOBAL source.
#define STAGE_TILE(DST, SRC, K0, NP, NT)                                   \
    _Pragma("unroll")                                                      \
    for (int p_ = 0; p_ < NP; ++p_) {                                      \
        const int base_ = p_*NT + wb;                                      \
        const int i_ = base_ + lane;                                       \
        const int row_ = i_ >> 3;                                          \
        const int cb_ = ((i_ & 7) ^ (row_ & 7)) * 8;                       \
        gload16((SRC) + (size_t)row_*768 + (K0) + cb_, &(DST)[base_*8]);   \
    }

// 2(m) x 4(n) frag compute, wave rows wm*32, cols wn*64 (64x128 tile) — proj.
#define COMPUTE_P(AS, BS)                                                  \
    {                                                                      \
        bf16x8_t a_[2][2], b_[2][4];                                       \
        _Pragma("unroll")                                                  \
        for (int ks_ = 0; ks_ < 2; ++ks_) {                                \
            _Pragma("unroll")                                              \
            for (int m_ = 0; m_ < 2; ++m_) {                               \
                const int ra_ = wm*32 + m_*16 + l15;                       \
                a_[ks_][m_] = *(const bf16x8_t*)&(AS)[ra_*64 + ((ks_*4 + lhi) ^ (ra_ & 7))*8]; \
            }                                                              \
            _Pragma("unroll")                                              \
            for (int n_ = 0; n_ < 4; ++n_) {                               \
                const int rb_ = wn*64 + n_*16 + l15;                       \
                b_[ks_][n_] = *(const bf16x8_t*)&(BS)[rb_*64 + ((ks_*4 + lhi) ^ (rb_ & 7))*8]; \
            }                                                              \
        }                                                                  \
        _Pragma("unroll")                                                  \
        for (int m_ = 0; m_ < 2; ++m_)                                     \
            _Pragma("unroll")                                              \
            for (int n_ = 0; n_ < 4; ++n_) {                               \
                acc[m_][n_] = __builtin_amdgcn_mfma_f32_16x16x32_bf16(a_[0][m_], b_[0][n_], acc[m_][n_], 0, 0, 0); \
                acc[m_][n_] = __builtin_amdgcn_mfma_f32_16x16x32_bf16(a_[1][m_], b_[1][n_], acc[m_][n_], 0, 0, 0); \
            }                                                              \
    }

// 4(m) x 2(n) frag compute, wave rows wm*64, cols wn*32 (128x64 tile) — qkv.
#define COMPUTE_Q2(AS, BS)                                                 \
    {                                                                      \
        bf16x8_t a_[2][4], b_[2][2];                                       \
        _Pragma("unroll")                                                  \
        for (int ks_ = 0; ks_ < 2; ++ks_) {                                \
            _Pragma("unroll")                                              \
            for (int m_ = 0; m_ < 4; ++m_) {                               \
                const int ra_ = wm*64 + m_*16 + l15;                       \
                a_[ks_][m_] = *(const bf16x8_t*)&(AS)[ra_*64 + ((ks_*4 + lhi) ^ (ra_ & 7))*8]; \
            }                                                              \
            _Pragma("unroll")                                              \
            for (int n_ = 0; n_ < 2; ++n_) {                               \
                const int rb_ = wn*32 + n_*16 + l15;                       \
                b_[ks_][n_] = *(const bf16x8_t*)&(BS)[rb_*64 + ((ks_*4 + lhi) ^ (rb_ & 7))*8]; \
            }                                                              \
        }                                                                  \
        _Pragma("unroll")                                                  \
        for (int m_ = 0; m_ < 4; ++m_)                                     \
            _Pragma("unroll")                                              \
            for (int n_ = 0; n_ < 2; ++n_) {                               \
                acc[m_][n_] = __builtin_amdgcn_mfma_f32_16x16x32_bf16(a_[0][m_], b_[0][n_], acc[m_][n_], 0, 0, 0); \
                acc[m_][n_] = __builtin_amdgcn_mfma_f32_16x16x32_bf16(a_[1][m_], b_[1][n_], acc[m_][n_], 0, 0, 0); \
            }                                                              \
    }

// ---------------- pre-pass: x f32 -> bf16 (same layout)
__global__ __launch_bounds__(256) void convert_x(
    const float* __restrict__ src, unsigned short* __restrict__ dst)
{
    const int i = blockIdx.x * 256 + threadIdx.x;
    const float4 v = ((const float4*)src)[i];
    ushort4 o; o.x = f2bf(v.x); o.y = f2bf(v.y); o.z = f2bf(v.z); o.w = f2bf(v.w);
    ((ushort4*)dst)[i] = o;
}

// ---------------- pre-pass: W [R][C] f32 -> Wt [C][R] bf16
__global__ __launch_bounds__(256) void transpose_cvt(
    const float* __restrict__ src, unsigned short* __restrict__ dst, int R, int C)
{
    __shared__ unsigned short tile[32][33];
    const int tx = threadIdx.x & 31, ty = threadIdx.x >> 5;
    const int bx = blockIdx.x, by = blockIdx.y;
    #pragma unroll
    for (int j = 0; j < 32; j += 8)
        tile[ty + j][tx] = f2bf(src[(size_t)(by*32 + ty + j) * C + bx*32 + tx]);
    __syncthreads();
    #pragma unroll
    for (int j = 0; j < 32; j += 8)
        dst[(size_t)(bx*32 + ty + j) * R + by*32 + tx] = tile[tx][ty + j];
}

// ---------------- GEMM1 (R14): 128x64 tile, 4 waves, 24KB, 6/CU
__global__ __launch_bounds__(256, 6) void gemm_qkv_bf16(
    const unsigned short* __restrict__ A, const unsigned short* __restrict__ Bt,
    const float* __restrict__ bias,
    unsigned short* __restrict__ q, unsigned short* __restrict__ kO,
    unsigned short* __restrict__ vT)
{
    __shared__ unsigned short As[128*64];   // 16KB
    __shared__ unsigned short Bs[64*64];    // 8KB
    const int tid = threadIdx.x;
    const int id = blockIdx.x;              // 2304 blocks, 2304%8==0
    // XCD-pinned A-slice; nb grouped by 8 (the 8 mb of this XCD share a
    // 96KB B-panel back-to-back, then it retires).
    const int xcd = id & 7, r = id >> 3;    // r 0..287
    const int nb = r >> 3;                  // 0..35 (one panel per 8 blocks)
    const int mb = (r & 7) * 8 + xcd;       // 0..63 (8 per XCD, pinned)
    const int n0 = nb * 64, m0 = mb * 128;

    const int lane = tid & 63, w = tid >> 6;
    const int l15 = lane & 15, lhi = lane >> 4;
    const int wm = w >> 1, wn = w & 1;      // 2x2 wave grid
    const int wb = tid & 192;

    const unsigned short* Ab = A  + (size_t)m0 * 768;
    const unsigned short* Bb = Bt + (size_t)n0 * 768;

    f32x4_t acc[4][2] = {};

    #pragma unroll 1
    for (int t = 0; t < 12; ++t) {
        STAGE_TILE(As, Ab, t*64, 4, 256)
        STAGE_TILE(Bs, Bb, t*64, 2, 256)
        WAIT0; BAR;
        COMPUTE_Q2(As, Bs)
        BAR;
    }

    // epilogue: qkv scatter. kk block-uniform (64 | 768).
    #pragma unroll
    for (int n = 0; n < 2; ++n) {
        const int gcol = n0 + wn*32 + n*16 + l15;         // 0..2303
        const int kk = gcol / 768;                        // 0=q,1=k,2=v
        const int rr = gcol - kk*768;
        const int h  = rr >> 6, d = rr & 63;
        const float bv = bias[gcol];
        const float sc = (kk == 0) ? 0.125f : 1.0f;
        #pragma unroll
        for (int m = 0; m < 4; ++m) {
            const int grow_base = m0 + wm*64 + m*16 + lhi*4;
            #pragma unroll
            for (int reg = 0; reg < 4; ++reg) {
                const int grow = grow_base + reg;         // b*1024+seq
                const int bb = grow >> 10, seq = grow & 1023;
                const unsigned short ov = f2bf((acc[m][n][reg] + bv) * sc);
                const size_t bh = (size_t)bb*12 + h;
                if (kk == 0)      q [ (bh*1024 + seq)*64 + d ] = ov;
                else if (kk == 1) kO[ (bh*1024 + seq)*64 + d ] = ov;
                else              vT[ (bh*64 + d)*1024 + seq ] = ov;
            }
        }
    }
}

// ---------------- Attention (R13): 8 waves, QBLK=128, shared K/V staging
__global__ __launch_bounds__(512, 6) void attn2(
    const unsigned short* __restrict__ q, const unsigned short* __restrict__ k,
    const unsigned short* __restrict__ vT, unsigned short* __restrict__ obuf)
{
    __shared__ unsigned short Ks[64 * 72];
    __shared__ unsigned short Vs[64 * 72];
    __shared__ unsigned short P[8][16 * 72];   // 36864 B total
    const int tid = threadIdx.x;
    const int id = blockIdx.x;                 // 768 blocks, 768%8==0
    const int swz = (id & 7) * 96 + (id >> 3);
    const int qt = swz & 7, bh = swz >> 3;     // 8 q-tiles of 128, 96 bh

    const int lane = tid & 63, w = tid >> 6;   // w 0..7
    const int l15 = lane & 15, lhi = lane >> 4;
    const unsigned short* qp = q  + (size_t)bh * 65536;
    const unsigned short* kp = k  + (size_t)bh * 65536;
    const unsigned short* vp = vT + (size_t)bh * 65536;  // [64 d][1024 n]

    bf16x8_t qf[2];
    const int qrow = qt*128 + w*16 + l15;
    #pragma unroll
    for (int ks = 0; ks < 2; ++ks)
        qf[ks] = *(const bf16x8_t*)(qp + (size_t)qrow*64 + ks*32 + lhi*8);

    f32x4_t acco[4] = {};
    float lsum[4] = {0.f, 0.f, 0.f, 0.f};
    unsigned short* Pw = P[w];

    const int r8 = tid >> 3, cb = (tid & 7) * 8;
    bf16x8_t kr, vr;
    kr = *(const bf16x8_t*)(kp + (size_t)r8*64 + cb);
    vr = *(const bf16x8_t*)(vp + (size_t)r8*1024 + cb);
    *(bf16x8_t*)&Ks[r8*72 + cb] = kr;
    *(bf16x8_t*)&Vs[r8*72 + cb] = vr;

    for (int kt = 0; kt < 16; ++kt) {
        __syncthreads();
        if (kt < 15) {
            kr = *(const bf16x8_t*)(kp + (size_t)((kt+1)*64 + r8)*64 + cb);
            vr = *(const bf16x8_t*)(vp + (size_t)r8*1024 + (kt+1)*64 + cb);
        }

        f32x4_t accs[4] = {};
        __builtin_amdgcn_s_setprio(1);
        #pragma unroll
        for (int c = 0; c < 4; ++c)
            #pragma unroll
            for (int ks = 0; ks < 2; ++ks) {
                bf16x8_t kf = *(const bf16x8_t*)&Ks[(c*16 + l15)*72 + ks*32 + lhi*8];
                accs[c] = __builtin_amdgcn_mfma_f32_16x16x32_bf16(qf[ks], kf, accs[c], 0, 0, 0);
            }
        __builtin_amdgcn_s_setprio(0);

        #pragma unroll
        for (int c = 0; c < 4; ++c)
            #pragma unroll
            for (int r = 0; r < 4; ++r) {
                const float pv = __expf(accs[c][r]);
                lsum[r] += pv;
                Pw[(lhi*4 + r)*72 + c*16 + l15] = f2bf(pv);
            }

        bf16x8_t pf[2];
        #pragma unroll
        for (int ks = 0; ks < 2; ++ks)
            pf[ks] = *(const bf16x8_t*)&Pw[l15*72 + ks*32 + lhi*8];
        __builtin_amdgcn_s_setprio(1);
        #pragma unroll
        for (int n = 0; n < 4; ++n)
            #pragma unroll
            for (int ks = 0; ks < 2; ++ks) {
                bf16x8_t vf = *(const bf16x8_t*)&Vs[(n*16 + l15)*72 + ks*32 + lhi*8];
                acco[n] = __builtin_amdgcn_mfma_f32_16x16x32_bf16(pf[ks], vf, acco[n], 0, 0, 0);
            }
        __builtin_amdgcn_s_setprio(0);

        __syncthreads();
        if (kt < 15) {
            *(bf16x8_t*)&Ks[r8*72 + cb] = kr;
            *(bf16x8_t*)&Vs[r8*72 + cb] = vr;
        }
    }

    #pragma unroll
    for (int r = 0; r < 4; ++r)
        #pragma unroll
        for (int off = 1; off <= 8; off <<= 1)
            lsum[r] += __shfl_xor(lsum[r], off, 64);

    const int b = bh / 12, h = bh % 12;
    #pragma unroll
    for (int n = 0; n < 4; ++n)
        #pragma unroll
        for (int r = 0; r < 4; ++r) {
            const int seq = qt*128 + w*16 + lhi*4 + r;
            obuf[((size_t)(b*1024 + seq))*768 + h*64 + n*16 + l15] = f2bf(acco[n][r] / lsum[r]);
        }
}

// ---------------- GEMM2 (R6 + 6/CU): 64x128 tile, 4 waves, 24KB buffer
__global__ __launch_bounds__(256, 6) void gemm_proj_bf16(
    const unsigned short* __restrict__ A, const unsigned short* __restrict__ Bt,
    const float* __restrict__ bias, float* __restrict__ out)
{
    __shared__ unsigned short As[64*64];
    __shared__ unsigned short Bs[128*64];
    const int tid = threadIdx.x;
    const int id = blockIdx.x;              // 768 blocks
    const int swz = (id & 7) * 96 + (id >> 3);
    const int n0 = (swz % 6) * 128, m0 = (swz / 6) * 64;

    const int lane = tid & 63, w = tid >> 6;
    const int l15 = lane & 15, lhi = lane >> 4;
    const int wm = w >> 1, wn = w & 1;
    const int wb = tid & 192;

    const unsigned short* Ab = A  + (size_t)m0 * 768;
    const unsigned short* Bb = Bt + (size_t)n0 * 768;

    f32x4_t acc[2][4] = {};

    #pragma unroll 1
    for (int t = 0; t < 12; ++t) {
        STAGE_TILE(As, Ab, t*64, 2, 256)
        STAGE_TILE(Bs, Bb, t*64, 4, 256)
        WAIT0; BAR;
        COMPUTE_P(As, Bs)
        BAR;
    }

    #pragma unroll
    for (int n = 0; n < 4; ++n) {
        const int gcol = n0 + wn*64 + n*16 + l15;
        const float bv = bias[gcol];
        #pragma unroll
        for (int m = 0; m < 2; ++m) {
            const int grow_base = m0 + wm*32 + m*16 + lhi*4;
            #pragma unroll
            for (int reg = 0; reg < 4; ++reg)
                out[(size_t)(grow_base + reg)*768 + gcol] = acc[m][n][reg] + bv;
        }
    }
}

extern "C" void kernel_launch(void* const* d_in, const int* in_sizes, int n_in,
                              void* d_out, int out_size, void* d_ws, size_t ws_size,
                              hipStream_t stream) {
    const float* x     = (const float*)d_in[0];
    const float* Wqkv  = (const float*)d_in[1];
    const float* bqkv  = (const float*)d_in[2];
    const float* Wproj = (const float*)d_in[3];
    const float* bproj = (const float*)d_in[4];
    float* out = (float*)d_out;
    unsigned short* ws = (unsigned short*)d_ws;

    unsigned short* xb    = ws;                       // 6291456
    unsigned short* obuf  = ws;                       // alias (xb dead after gemm_qkv)
    unsigned short* wqt   = ws + 6291456u;            // 1769472
    unsigned short* wpt   = ws + 8060928u;            // 589824
    unsigned short* qb    = ws + 8650752u;            // 6291456
    unsigned short* kb    = ws + 14942208u;           // 6291456
    unsigned short* vTb   = ws + 21233664u;           // 6291456

    convert_x     <<<6144, 256, 0, stream>>>(x, xb);
    transpose_cvt <<<dim3(72, 24), 256, 0, stream>>>(Wqkv, wqt, 768, 2304);
    transpose_cvt <<<dim3(24, 24), 256, 0, stream>>>(Wproj, wpt, 768, 768);
    gemm_qkv_bf16 <<<2304, 256, 0, stream>>>(xb, wqt, bqkv, qb, kb, vTb);
    attn2         <<<768,  512, 0, stream>>>(qb, kb, vTb, obuf);
    gemm_proj_bf16<<<768,  256, 0, stream>>>(obuf, wpt, bproj, out);
}